// Round 16
// baseline (472.483 us; speedup 1.0000x reference)
//
#include <hip/hip_runtime.h>
#include <math.h>

#define Bn 32
#define Fn 1024
#define Dn 256
#define Hn 4
#define En 64
#define FFn 4096
#define LN_EPS 1e-5f
#define NBLK 256
#define NTHR 512

__device__ __forceinline__ float wsum(float v) {
#pragma unroll
    for (int off = 32; off; off >>= 1) v += __shfl_xor(v, off, 64);
    return v;
}
__device__ __forceinline__ float4 xr4(float4 v, int m) {
    v.x += __shfl_xor(v.x, m, 64);
    v.y += __shfl_xor(v.y, m, 64);
    v.z += __shfl_xor(v.z, m, 64);
    v.w += __shfl_xor(v.w, m, 64);
    return v;
}
#define FMA4(A, S, B) \
    A.x = fmaf(S, B.x, A.x); A.y = fmaf(S, B.y, A.y); \
    A.z = fmaf(S, B.z, A.z); A.w = fmaf(S, B.w, A.w);

// parallel flag-array grid barrier: per-block release flag (own cache line),
// block 0 polls all in parallel, single release word. Epoch-valued, no reset.
__device__ __forceinline__ void gbar(unsigned* flags, unsigned* rel,
                                     unsigned target, int bid, int tid) {
    __syncthreads();
    __threadfence();
    if (tid == 0)
        __hip_atomic_store(&flags[(size_t)bid * 32], target, __ATOMIC_RELEASE,
                           __HIP_MEMORY_SCOPE_AGENT);
    if (bid == 0) {
        if (tid < NBLK) {
            while (__hip_atomic_load(&flags[(size_t)tid * 32], __ATOMIC_ACQUIRE,
                                     __HIP_MEMORY_SCOPE_AGENT) != target)
                __builtin_amdgcn_s_sleep(2);
        }
        __syncthreads();
        if (tid == 0)
            __hip_atomic_store(rel, target, __ATOMIC_RELEASE,
                               __HIP_MEMORY_SCOPE_AGENT);
    }
    if (tid == 0) {
        while (__hip_atomic_load(rel, __ATOMIC_ACQUIRE,
                                 __HIP_MEMORY_SCOPE_AGENT) != target)
            __builtin_amdgcn_s_sleep(2);
    }
    __syncthreads();
    __threadfence();
}

__global__ __launch_bounds__(NTHR) void fused(
    const float* __restrict__ x, const float* __restrict__ emb,
    const float* __restrict__ Wq, const float* __restrict__ Wk,
    const float* __restrict__ Wv, const float* __restrict__ Wo,
    const float* __restrict__ bo, const float* __restrict__ g1,
    const float* __restrict__ b1, const float* __restrict__ g2,
    const float* __restrict__ b2, const float* __restrict__ W1,
    const float* __restrict__ bf1, const float* __restrict__ W2,
    const float* __restrict__ bf2,
    float* __restrict__ EqT, float* __restrict__ Ekg, float* __restrict__ Evo,
    float* __restrict__ hbuf, float* __restrict__ TT8, float* __restrict__ h2T,
    float* __restrict__ C1h, unsigned* __restrict__ bar,
    float* __restrict__ out)
{
    __shared__ float smem[10624];   // 42.5 KB, reused per phase
    const int bid = blockIdx.x, tid = threadIdx.x;
    const int wid = tid >> 6, lane = tid & 63;
    unsigned* epochp = bar;
    unsigned* rel = bar + 32;
    unsigned* flags = bar + 64;
    if (tid == 0)
        ((unsigned*)smem)[0] = __hip_atomic_load(epochp, __ATOMIC_RELAXED,
                                                 __HIP_MEMORY_SCOPE_AGENT);
    __syncthreads();
    const unsigned E = ((unsigned*)smem)[0];
    __syncthreads();

    // ================= P1: LN1 (blocks 0..31) then proj (all 256) ==========
    if (bid < Bn) {
        float2 v = ((const float2*)(x + bid * Fn))[tid];
        float s = wsum(v.x + v.y);
        if (lane == 0) smem[wid] = s;
        __syncthreads();
        float mu = 0.f;
#pragma unroll
        for (int w = 0; w < 8; w++) mu += smem[w];
        mu *= (1.f / Fn);
        float dx = v.x - mu, dy = v.y - mu;
        float vs = wsum(dx * dx + dy * dy);
        __syncthreads();
        if (lane == 0) smem[wid] = vs;
        __syncthreads();
        float var = 0.f;
#pragma unroll
        for (int w = 0; w < 8; w++) var += smem[w];
        var *= (1.f / Fn);
        float rs = rsqrtf(var + LN_EPS);
        float2 gv = ((const float2*)g1)[tid];
        float2 bv = ((const float2*)b1)[tid];
        float2 o;
        o.x = dx * rs * gv.x + bv.x;
        o.y = dy * rs * gv.y + bv.y;
        ((float2*)(hbuf + bid * Fn))[tid] = o;
        __syncthreads();
    }
    {
        float* semb = smem;             // 4096
        float* swb = smem + 4096;       // 2*3*1088
        const int h = bid >> 6, f0 = (bid & 63) * 16;
        const float4* e4p = (const float4*)(emb + (size_t)f0 * Dn);
        ((float4*)semb)[tid] = e4p[tid];
        ((float4*)semb)[tid + 512] = e4p[tid + 512];
        const int es = lane & 15, gs = lane >> 4;
        float4 wo4 = *(const float4*)&Wo[h * En + es * 4];
        const float* wqa = Wq + (size_t)h * Dn * En;
        const float* wka = Wk + (size_t)h * Dn * En;
        const float* wva = Wv + (size_t)h * Dn * En;
        const int sd = (tid & 255) >> 4;
        const int se = (tid & 15) * 4;
        const bool lo = tid < 256;
        float4 rq, rk, rv;
        const int fl = wid * 2;
        float4 aq0 = {0,0,0,0}, aq1 = {0,0,0,0};
        float4 ak0 = {0,0,0,0}, ak1 = {0,0,0,0};
        float4 av0 = {0,0,0,0}, av1 = {0,0,0,0};
        {
            size_t off = ((size_t)sd) * En + se;
            if (lo) rq = *(const float4*)&wqa[off];
            else { rk = *(const float4*)&wka[off]; rv = *(const float4*)&wva[off]; }
            if (lo) *(float4*)&swb[0 * 1088 + sd * 68 + se] = rq;
            else {
                *(float4*)&swb[1 * 1088 + sd * 68 + se] = rk;
                *(float4*)&swb[2 * 1088 + sd * 68 + se] = rv;
            }
        }
        __syncthreads();
        for (int c = 0; c < 16; c++) {
            if (c < 15) {
                size_t off = ((size_t)((c + 1) * 16 + sd)) * En + se;
                if (lo) rq = *(const float4*)&wqa[off];
                else { rk = *(const float4*)&wka[off]; rv = *(const float4*)&wva[off]; }
            }
            const int pb = c & 1;
            const float* bq = swb + (pb * 3 + 0) * 1088;
            const float* bk = swb + (pb * 3 + 1) * 1088;
            const float* bv_ = swb + (pb * 3 + 2) * 1088;
#pragma unroll
            for (int d0 = 0; d0 < 16; d0 += 4) {
                int d = d0 + gs;
                float4 q4 = *(const float4*)&bq[d * 68 + es * 4];
                float4 k4 = *(const float4*)&bk[d * 68 + es * 4];
                float4 v4 = *(const float4*)&bv_[d * 68 + es * 4];
                float e0 = semb[fl * 256 + c * 16 + d];
                float e1 = semb[(fl + 1) * 256 + c * 16 + d];
                FMA4(aq0, e0, q4); FMA4(aq1, e1, q4);
                FMA4(ak0, e0, k4); FMA4(ak1, e1, k4);
                FMA4(av0, e0, v4); FMA4(av1, e1, v4);
            }
            if (c < 15) {
                const int nb = (c + 1) & 1;
                __syncthreads();
                if (lo) *(float4*)&swb[(nb * 3 + 0) * 1088 + sd * 68 + se] = rq;
                else {
                    *(float4*)&swb[(nb * 3 + 1) * 1088 + sd * 68 + se] = rk;
                    *(float4*)&swb[(nb * 3 + 2) * 1088 + sd * 68 + se] = rv;
                }
                __syncthreads();
            }
        }
        aq0 = xr4(aq0, 16); aq0 = xr4(aq0, 32);
        aq1 = xr4(aq1, 16); aq1 = xr4(aq1, 32);
        ak0 = xr4(ak0, 16); ak0 = xr4(ak0, 32);
        ak1 = xr4(ak1, 16); ak1 = xr4(ak1, 32);
        av0 = xr4(av0, 16); av0 = xr4(av0, 32);
        av1 = xr4(av1, 16); av1 = xr4(av1, 32);
        float p0 = av0.x * wo4.x + av0.y * wo4.y + av0.z * wo4.z + av0.w * wo4.w;
        float p1 = av1.x * wo4.x + av1.y * wo4.y + av1.z * wo4.z + av1.w * wo4.w;
#pragma unroll
        for (int m = 1; m < 16; m <<= 1) {
            p0 += __shfl_xor(p0, m, 64);
            p1 += __shfl_xor(p1, m, 64);
        }
        int f = f0 + fl;
        if (lane == 0) { Evo[h * Fn + f] = p0; Evo[h * Fn + f + 1] = p1; }
        if (gs == 0) {
            *(float4*)&Ekg[((size_t)h * Fn + f) * En + es * 4] = ak0;
            *(float4*)&Ekg[((size_t)h * Fn + f + 1) * En + es * 4] = ak1;
            const float sc = 0.125f;
            EqT[((size_t)h * En + es * 4 + 0) * Fn + f] = aq0.x * sc;
            EqT[((size_t)h * En + es * 4 + 1) * Fn + f] = aq0.y * sc;
            EqT[((size_t)h * En + es * 4 + 2) * Fn + f] = aq0.z * sc;
            EqT[((size_t)h * En + es * 4 + 3) * Fn + f] = aq0.w * sc;
            EqT[((size_t)h * En + es * 4 + 0) * Fn + f + 1] = aq1.x * sc;
            EqT[((size_t)h * En + es * 4 + 1) * Fn + f + 1] = aq1.y * sc;
            EqT[((size_t)h * En + es * 4 + 2) * Fn + f + 1] = aq1.z * sc;
            EqT[((size_t)h * En + es * 4 + 3) * Fn + f + 1] = aq1.w * sc;
        }
    }
    gbar(flags, rel, E + 1u, bid, tid);

    // ================= P2: TT8 (2048 wave-units over 256 blocks) ===========
    {
        const int u = bid * 8 + wid;
        const int gc = u >> 8, hh = (u >> 6) & 3, c = u & 63;
        const int es = lane & 15, gs = lane >> 4;
        const float* ekb = Ekg + ((size_t)hh * Fn + gc * 128) * En + es * 4;
        float4 acc = {0, 0, 0, 0};
        if (c < Bn) {
            const float* rp = hbuf + (size_t)c * Fn + gc * 128;
#pragma unroll 8
            for (int g0 = 0; g0 < 128; g0 += 4) {
                int g = g0 + gs;
                float r = rp[g];
                float4 ek = *(const float4*)&ekb[(size_t)g * En];
                FMA4(acc, r, ek);
            }
        } else {
            const float* hp = hbuf + (size_t)(c - Bn) * Fn + gc * 128;
            const float* ep = Evo + hh * Fn + gc * 128;
#pragma unroll 8
            for (int g0 = 0; g0 < 128; g0 += 4) {
                int g = g0 + gs;
                float hv = hp[g];
                float r = hv * hv * ep[g];
                float4 ek = *(const float4*)&ekb[(size_t)g * En];
                FMA4(acc, r, ek);
            }
        }
        acc = xr4(acc, 16); acc = xr4(acc, 32);
        if (gs == 0)
            *(float4*)&TT8[(((size_t)gc * Hn + hh) * 64 + c) * 64 + es * 4] = acc;
    }
    gbar(flags, rel, E + 2u, bid, tid);

    // ================= P3: attn combine + LN2 (blocks 0..31) ===============
    if (bid < Bn) {
        const int b = bid;
        {
            int cIsN = tid >> 8, hh = (tid >> 6) & 3, e = tid & 63;
            int c = cIsN ? (Bn + b) : b;
            float v = 0.f;
#pragma unroll
            for (int gc = 0; gc < 8; gc++)
                v += TT8[(((size_t)gc * Hn + hh) * 64 + c) * 64 + e];
            smem[tid] = v;
        }
        float2 hv2 = *(const float2*)&hbuf[b * Fn + tid * 2];
        float pp[Hn];
#pragma unroll
        for (int hh = 0; hh < Hn; hh++) {
            float2 ev2 = *(const float2*)&Evo[hh * Fn + tid * 2];
            pp[hh] = hv2.x * ev2.x + hv2.y * ev2.y;
        }
#pragma unroll
        for (int hh = 0; hh < Hn; hh++) {
            pp[hh] = wsum(pp[hh]);
            if (lane == 0) smem[512 + hh * 8 + wid] = pp[hh];
        }
        __syncthreads();
        if (tid < Hn) {
            float s = 0.f;
#pragma unroll
            for (int w = 0; w < 8; w++) s += smem[512 + tid * 8 + w];
            smem[552 + tid] = s;
        }
        __syncthreads();
        float bov = bo[0];
        float2 xv = *(const float2*)&x[b * Fn + tid * 2];
        xv.x += bov; xv.y += bov;
#pragma unroll
        for (int hh = 0; hh < Hn; hh++) {
            float zdx = 0, zdy = 0, znx = 0, zny = 0;
            const float* eqb = EqT + (size_t)hh * En * Fn + tid * 2;
#pragma unroll 8
            for (int e = 0; e < En; e++) {
                float2 eq = *(const float2*)&eqb[(size_t)e * Fn];
                float td = smem[hh * 64 + e];
                float tn = smem[256 + hh * 64 + e];
                zdx = fmaf(eq.x, td, zdx); zdy = fmaf(eq.y, td, zdy);
                znx = fmaf(eq.x, tn, znx); zny = fmaf(eq.y, tn, zny);
            }
            float s0 = smem[552 + hh];
            xv.x += (s0 + hv2.x * znx) / (1024.0f + hv2.x * zdx);
            xv.y += (s0 + hv2.y * zny) / (1024.0f + hv2.y * zdy);
        }
        float s = wsum(xv.x + xv.y);
        if (lane == 0) smem[544 + wid] = s;
        __syncthreads();
        float mu = 0.f;
#pragma unroll
        for (int w = 0; w < 8; w++) mu += smem[544 + w];
        mu *= (1.f / Fn);
        float dx = xv.x - mu, dy = xv.y - mu;
        float vs = wsum(dx * dx + dy * dy);
        __syncthreads();
        if (lane == 0) smem[544 + wid] = vs;
        __syncthreads();
        float var = 0.f;
#pragma unroll
        for (int w = 0; w < 8; w++) var += smem[544 + w];
        var *= (1.f / Fn);
        float rs = rsqrtf(var + LN_EPS);
        float2 bf2v = *(const float2*)&bf2[tid * 2];
        float2 ov;
        ov.x = xv.x + bf2v.x;
        ov.y = xv.y + bf2v.y;
        *(float2*)&out[b * Fn + tid * 2] = ov;
        float2 g2v = ((const float2*)g2)[tid];
        float2 b2v = ((const float2*)b2)[tid];
        h2T[(size_t)(tid * 2) * Bn + b] = dx * rs * g2v.x + b2v.x;
        h2T[(size_t)(tid * 2 + 1) * Bn + b] = dy * rs * g2v.y + b2v.y;
    }
    gbar(flags, rel, E + 3u, bid, tid);

    // ================= P4: ffn1 split-K-2 -> C1h (256 blocks) ==============
    {
        float* sred = smem;   // [8][64][20] = 10240
        const int jg = bid & 127, half = bid >> 7;
        const int jq = lane & 7, bg = (lane >> 3) * 4;
        const float* wb = W1 + (size_t)(half * 512 + wid * 64) * FFn + jg * 32 + jq * 4;
        const float* hb = h2T + (size_t)(half * 512 + wid * 64) * Bn + bg;
        float4 a0 = {0,0,0,0}, a1 = {0,0,0,0}, a2 = {0,0,0,0}, a3 = {0,0,0,0};
#pragma unroll 8
        for (int f = 0; f < 64; f++) {
            float4 w4 = *(const float4*)&wb[(size_t)f * FFn];
            float4 h4 = *(const float4*)&hb[(size_t)f * Bn];
            FMA4(a0, h4.x, w4);
            FMA4(a1, h4.y, w4);
            FMA4(a2, h4.z, w4);
            FMA4(a3, h4.w, w4);
        }
        float* sp_ = &sred[(wid * 64 + lane) * 20];
        *(float4*)&sp_[0]  = a0;
        *(float4*)&sp_[4]  = a1;
        *(float4*)&sp_[8]  = a2;
        *(float4*)&sp_[12] = a3;
        __syncthreads();
#pragma unroll
        for (int r = 0; r < 2; r++) {
            int v = r * 512 + tid;
            int vl = v >> 4, k = v & 15;
            float acc = 0.f;
#pragma unroll
            for (int w = 0; w < 8; w++) acc += sred[(w * 64 + vl) * 20 + k];
            int jq2 = vl & 7, bgr = vl >> 3;
            int j = jg * 32 + jq2 * 4 + (k & 3);
            int bb = bgr * 4 + (k >> 2);
            C1h[((size_t)half * FFn + j) * Bn + bb] = acc;
        }
    }
    gbar(flags, rel, E + 4u, bid, tid);

    // ================= P5: ffn2 + gelu stage (256 blocks) ==================
    {
        float* ug = smem;   // 8192: [jj][b]
        const int it = bid & 15, jc = bid >> 4;
        const float kk = 0.70710678118654752f;
        const float4* b0p = (const float4*)(C1h + (size_t)jc * 256 * Bn);
        const float4* b1p = (const float4*)(C1h + ((size_t)FFn + jc * 256) * Bn);
#pragma unroll
        for (int k = 0; k < 4; k++) {
            int idx = k * 512 + tid;
            float4 s = b0p[idx];
            float4 c = b1p[idx];
            s.x += c.x; s.y += c.y; s.z += c.z; s.w += c.w;
            float bb = bf1[jc * 256 + (idx >> 3)];
            s.x += bb; s.y += bb; s.z += bb; s.w += bb;
            float4 g;
            g.x = 0.5f * s.x * (1.f + erff(s.x * kk));
            g.y = 0.5f * s.y * (1.f + erff(s.y * kk));
            g.z = 0.5f * s.z * (1.f + erff(s.z * kk));
            g.w = 0.5f * s.w * (1.f + erff(s.w * kk));
            ((float4*)ug)[idx] = g;
        }
        __syncthreads();
        const int jg = lane >> 4, il = lane & 15;
        const int i0 = it * 64 + il * 4;
        const int bg = wid * 4;
        const float* wb = W2 + (size_t)(jc * 256 + jg) * Fn + i0;
        float4 a0 = {0,0,0,0}, a1 = {0,0,0,0}, a2 = {0,0,0,0}, a3 = {0,0,0,0};
#pragma unroll 8
        for (int jj0 = 0; jj0 < 256; jj0 += 4) {
            float4 w4 = *(const float4*)&wb[(size_t)jj0 * Fn];
            float4 u4 = *(const float4*)&ug[(jj0 + jg) * 32 + bg];
            FMA4(a0, u4.x, w4);
            FMA4(a1, u4.y, w4);
            FMA4(a2, u4.z, w4);
            FMA4(a3, u4.w, w4);
        }
        a0 = xr4(a0, 16); a0 = xr4(a0, 32);
        a1 = xr4(a1, 16); a1 = xr4(a1, 32);
        a2 = xr4(a2, 16); a2 = xr4(a2, 32);
        a3 = xr4(a3, 16); a3 = xr4(a3, 32);
        if (jg == 0) {
            float* ob = out + (size_t)bg * Fn + i0;
            atomicAdd(&ob[0 * Fn + 0], a0.x); atomicAdd(&ob[0 * Fn + 1], a0.y);
            atomicAdd(&ob[0 * Fn + 2], a0.z); atomicAdd(&ob[0 * Fn + 3], a0.w);
            atomicAdd(&ob[1 * Fn + 0], a1.x); atomicAdd(&ob[1 * Fn + 1], a1.y);
            atomicAdd(&ob[1 * Fn + 2], a1.z); atomicAdd(&ob[1 * Fn + 3], a1.w);
            atomicAdd(&ob[2 * Fn + 0], a2.x); atomicAdd(&ob[2 * Fn + 1], a2.y);
            atomicAdd(&ob[2 * Fn + 2], a2.z); atomicAdd(&ob[2 * Fn + 3], a2.w);
            atomicAdd(&ob[3 * Fn + 0], a3.x); atomicAdd(&ob[3 * Fn + 1], a3.y);
            atomicAdd(&ob[3 * Fn + 2], a3.z); atomicAdd(&ob[3 * Fn + 3], a3.w);
        }
    }
    if (bid == 0 && tid == 0)
        __hip_atomic_store(epochp, E + 4u, __ATOMIC_RELAXED,
                           __HIP_MEMORY_SCOPE_AGENT);
}

extern "C" void kernel_launch(void* const* d_in, const int* in_sizes, int n_in,
                              void* d_out, int out_size, void* d_ws, size_t ws_size,
                              hipStream_t stream) {
    (void)in_sizes; (void)n_in; (void)out_size; (void)ws_size;
    const float* x   = (const float*)d_in[0];
    const float* emb = (const float*)d_in[1];
    const float* Wq  = (const float*)d_in[2];
    const float* Wk  = (const float*)d_in[3];
    const float* Wv  = (const float*)d_in[4];
    const float* Wo  = (const float*)d_in[5];
    const float* bo  = (const float*)d_in[6];
    const float* g1  = (const float*)d_in[7];
    const float* b1  = (const float*)d_in[8];
    const float* g2  = (const float*)d_in[9];
    const float* b2  = (const float*)d_in[10];
    const float* W1  = (const float*)d_in[11];
    const float* bf1 = (const float*)d_in[12];
    const float* W2  = (const float*)d_in[13];
    const float* bf2 = (const float*)d_in[14];
    float* out = (float*)d_out;

    float* ws = (float*)d_ws;
    size_t o = 0;
    float* EqT  = ws + o; o += (size_t)Hn * En * Fn;        // 262144
    float* Ekg  = ws + o; o += (size_t)Hn * Fn * En;        // 262144
    float* Evo  = ws + o; o += (size_t)Hn * Fn;             // 4096
    float* hbuf = ws + o; o += (size_t)Bn * Fn;             // 32768
    float* TT8  = ws + o; o += (size_t)8 * Hn * 64 * 64;    // 131072
    float* h2T  = ws + o; o += (size_t)Fn * Bn;             // 32768
    float* C1h  = ws + o; o += (size_t)2 * FFn * Bn;        // 262144

    unsigned* bar = (unsigned*)((char*)d_ws + (8u << 20));  // past arrays

    fused<<<dim3(NBLK), NTHR, 0, stream>>>(
        x, emb, Wq, Wk, Wv, Wo, bo, g1, b1, g2, b2, W1, bf1, W2, bf2,
        EqT, Ekg, Evo, hbuf, TT8, h2T, C1h, bar, out);
}

// Round 17
// 70.643 us; speedup vs baseline: 6.6883x; 6.6883x over previous
//
#include <hip/hip_runtime.h>
#include <math.h>

#define Bn 32
#define Fn 1024
#define Dn 256
#define Hn 4
#define En 64
#define FFn 4096
#define LN_EPS 1e-5f

__device__ __forceinline__ float wsum(float v) {
#pragma unroll
    for (int off = 32; off; off >>= 1) v += __shfl_xor(v, off, 64);
    return v;
}
__device__ __forceinline__ float4 xr4(float4 v, int m) {
    v.x += __shfl_xor(v.x, m, 64);
    v.y += __shfl_xor(v.y, m, 64);
    v.z += __shfl_xor(v.z, m, 64);
    v.w += __shfl_xor(v.w, m, 64);
    return v;
}
#define FMA4(A, S, B) \
    A.x = fmaf(S, B.x, A.x); A.y = fmaf(S, B.y, A.y); \
    A.z = fmaf(S, B.z, A.z); A.w = fmaf(S, B.w, A.w);

// ---- k1: {LN1 (blocks 0..31)} | {proj with LDS-staged double-buffered W chunks}
__global__ __launch_bounds__(512) void k1(
    const float* __restrict__ x, const float* __restrict__ g1,
    const float* __restrict__ b1, const float* __restrict__ emb,
    const float* __restrict__ Wq, const float* __restrict__ Wk,
    const float* __restrict__ Wv, const float* __restrict__ Wo,
    float* __restrict__ hbuf, float* __restrict__ EqT,
    float* __restrict__ Ekg, float* __restrict__ Evo)
{
    __shared__ float semb[4096];        // 16 KB: emb tile / LN reduce scratch
    __shared__ float swb[2][3][1088];   // 26.1 KB
    const int bid = blockIdx.x, tid = threadIdx.x;
    const int wid = tid >> 6, lane = tid & 63;
    if (bid < Bn) {
        float2 v = ((const float2*)(x + bid * Fn))[tid];
        float s = wsum(v.x + v.y);
        if (lane == 0) semb[wid] = s;
        __syncthreads();
        float mu = 0.f;
#pragma unroll
        for (int w = 0; w < 8; w++) mu += semb[w];
        mu *= (1.f / Fn);
        float dx = v.x - mu, dy = v.y - mu;
        float vs = wsum(dx * dx + dy * dy);
        __syncthreads();
        if (lane == 0) semb[wid] = vs;
        __syncthreads();
        float var = 0.f;
#pragma unroll
        for (int w = 0; w < 8; w++) var += semb[w];
        var *= (1.f / Fn);
        float rs = rsqrtf(var + LN_EPS);
        float2 gv = ((const float2*)g1)[tid];
        float2 bv = ((const float2*)b1)[tid];
        float2 o;
        o.x = dx * rs * gv.x + bv.x;
        o.y = dy * rs * gv.y + bv.y;
        ((float2*)(hbuf + bid * Fn))[tid] = o;
    } else {
        const int idx = bid - Bn;        // 0..255
        const int h = idx >> 6, f0 = (idx & 63) * 16;
        const float4* e4 = (const float4*)(emb + (size_t)f0 * Dn);
        float4* s4 = (float4*)semb;
        s4[tid] = e4[tid];
        s4[tid + 512] = e4[tid + 512];
        const int es = lane & 15, gs = lane >> 4;
        float4 wo4 = *(const float4*)&Wo[h * En + es * 4];
        const float* wqa = Wq + (size_t)h * Dn * En;
        const float* wka = Wk + (size_t)h * Dn * En;
        const float* wva = Wv + (size_t)h * Dn * En;
        const int sd = (tid & 255) >> 4;
        const int se = (tid & 15) * 4;
        const bool lo = tid < 256;
        float4 rq, rk, rv;
        const int fl = wid * 2;
        float4 aq0 = {0,0,0,0}, aq1 = {0,0,0,0};
        float4 ak0 = {0,0,0,0}, ak1 = {0,0,0,0};
        float4 av0 = {0,0,0,0}, av1 = {0,0,0,0};
        {
            size_t off = ((size_t)sd) * En + se;
            if (lo) rq = *(const float4*)&wqa[off];
            else { rk = *(const float4*)&wka[off]; rv = *(const float4*)&wva[off]; }
            if (lo) *(float4*)&swb[0][0][sd * 68 + se] = rq;
            else {
                *(float4*)&swb[0][1][sd * 68 + se] = rk;
                *(float4*)&swb[0][2][sd * 68 + se] = rv;
            }
        }
        __syncthreads();
        for (int c = 0; c < 16; c++) {
            if (c < 15) {
                size_t off = ((size_t)((c + 1) * 16 + sd)) * En + se;
                if (lo) rq = *(const float4*)&wqa[off];
                else { rk = *(const float4*)&wka[off]; rv = *(const float4*)&wva[off]; }
            }
            const int pb = c & 1;
            const float* bq = swb[pb][0];
            const float* bk = swb[pb][1];
            const float* bv_ = swb[pb][2];
#pragma unroll
            for (int d0 = 0; d0 < 16; d0 += 4) {
                int d = d0 + gs;
                float4 q4 = *(const float4*)&bq[d * 68 + es * 4];
                float4 k4 = *(const float4*)&bk[d * 68 + es * 4];
                float4 v4 = *(const float4*)&bv_[d * 68 + es * 4];
                float e0 = semb[fl * 256 + c * 16 + d];
                float e1 = semb[(fl + 1) * 256 + c * 16 + d];
                FMA4(aq0, e0, q4); FMA4(aq1, e1, q4);
                FMA4(ak0, e0, k4); FMA4(ak1, e1, k4);
                FMA4(av0, e0, v4); FMA4(av1, e1, v4);
            }
            if (c < 15) {
                const int nb = (c + 1) & 1;
                __syncthreads();
                if (lo) *(float4*)&swb[nb][0][sd * 68 + se] = rq;
                else {
                    *(float4*)&swb[nb][1][sd * 68 + se] = rk;
                    *(float4*)&swb[nb][2][sd * 68 + se] = rv;
                }
                __syncthreads();
            }
        }
        aq0 = xr4(aq0, 16); aq0 = xr4(aq0, 32);
        aq1 = xr4(aq1, 16); aq1 = xr4(aq1, 32);
        ak0 = xr4(ak0, 16); ak0 = xr4(ak0, 32);
        ak1 = xr4(ak1, 16); ak1 = xr4(ak1, 32);
        av0 = xr4(av0, 16); av0 = xr4(av0, 32);
        av1 = xr4(av1, 16); av1 = xr4(av1, 32);
        float p0 = av0.x * wo4.x + av0.y * wo4.y + av0.z * wo4.z + av0.w * wo4.w;
        float p1 = av1.x * wo4.x + av1.y * wo4.y + av1.z * wo4.z + av1.w * wo4.w;
#pragma unroll
        for (int m = 1; m < 16; m <<= 1) {
            p0 += __shfl_xor(p0, m, 64);
            p1 += __shfl_xor(p1, m, 64);
        }
        int f = f0 + fl;
        if (lane == 0) { Evo[h * Fn + f] = p0; Evo[h * Fn + f + 1] = p1; }
        if (gs == 0) {
            *(float4*)&Ekg[((size_t)h * Fn + f) * En + es * 4] = ak0;
            *(float4*)&Ekg[((size_t)h * Fn + f + 1) * En + es * 4] = ak1;
            const float sc = 0.125f;
            EqT[((size_t)h * En + es * 4 + 0) * Fn + f] = aq0.x * sc;
            EqT[((size_t)h * En + es * 4 + 1) * Fn + f] = aq0.y * sc;
            EqT[((size_t)h * En + es * 4 + 2) * Fn + f] = aq0.z * sc;
            EqT[((size_t)h * En + es * 4 + 3) * Fn + f] = aq0.w * sc;
            EqT[((size_t)h * En + es * 4 + 0) * Fn + f + 1] = aq1.x * sc;
            EqT[((size_t)h * En + es * 4 + 1) * Fn + f + 1] = aq1.y * sc;
            EqT[((size_t)h * En + es * 4 + 2) * Fn + f + 1] = aq1.z * sc;
            EqT[((size_t)h * En + es * 4 + 3) * Fn + f + 1] = aq1.w * sc;
        }
    }
}

// ---- k2: TT8[gc][h][c][e] (512 blocks) ----
__global__ __launch_bounds__(256) void k2(
    const float* __restrict__ hbuf, const float* __restrict__ Evo,
    const float* __restrict__ Ekg, float* __restrict__ TT8)
{
    const int bid = blockIdx.x, tid = threadIdx.x;
    const int wid = tid >> 6, lane = tid & 63;
    const int u = bid * 4 + wid;                  // 0..2047
    const int gc = u >> 8, hh = (u >> 6) & 3, c = u & 63;
    const int es = lane & 15, gs = lane >> 4;
    const float* ekb = Ekg + ((size_t)hh * Fn + gc * 128) * En + es * 4;
    float4 acc = {0, 0, 0, 0};
    if (c < Bn) {
        const float* rp = hbuf + (size_t)c * Fn + gc * 128;
#pragma unroll 8
        for (int g0 = 0; g0 < 128; g0 += 4) {
            int g = g0 + gs;
            float r = rp[g];
            float4 ek = *(const float4*)&ekb[(size_t)g * En];
            FMA4(acc, r, ek);
        }
    } else {
        const float* hp = hbuf + (size_t)(c - Bn) * Fn + gc * 128;
        const float* ep = Evo + hh * Fn + gc * 128;
#pragma unroll 8
        for (int g0 = 0; g0 < 128; g0 += 4) {
            int g = g0 + gs;
            float hv = hp[g];
            float r = hv * hv * ep[g];
            float4 ek = *(const float4*)&ekb[(size_t)g * En];
            FMA4(acc, r, ek);
        }
    }
    acc = xr4(acc, 16); acc = xr4(acc, 32);
    if (gs == 0)
        *(float4*)&TT8[(((size_t)gc * Hn + hh) * 64 + c) * 64 + es * 4] = acc;
}

// ---- k3: attn combine + residual + LN2; writes out-base (=xmid+bf2) and h2T
__global__ __launch_bounds__(1024) void k3(
    const float* __restrict__ x, const float* __restrict__ hbuf,
    const float* __restrict__ TT8, const float* __restrict__ EqT,
    const float* __restrict__ Evo, const float* __restrict__ bo,
    const float* __restrict__ g2, const float* __restrict__ b2,
    const float* __restrict__ bf2,
    float* __restrict__ out, float* __restrict__ h2T)
{
    __shared__ float tt[512];      // [cIsN][h][e]
    __shared__ float sp[Hn][16];
    __shared__ float red[16];
    __shared__ float s0l[Hn];
    const int b = blockIdx.x, tid = threadIdx.x;
    const int wid = tid >> 6, lane = tid & 63;
    if (tid < 512) {
        int cIsN = tid >> 8, hh = (tid >> 6) & 3, e = tid & 63;
        int c = cIsN ? (Bn + b) : b;
        float v = 0.f;
#pragma unroll
        for (int gc = 0; gc < 8; gc++)
            v += TT8[(((size_t)gc * Hn + hh) * 64 + c) * 64 + e];
        tt[tid] = v;
    }
    const int f = tid;
    float hf = hbuf[b * Fn + f];
    float pp[Hn];
#pragma unroll
    for (int hh = 0; hh < Hn; hh++) pp[hh] = hf * Evo[hh * Fn + f];
#pragma unroll
    for (int hh = 0; hh < Hn; hh++) {
        float t = wsum(pp[hh]);
        if (lane == 0) sp[hh][wid] = t;
    }
    __syncthreads();
    if (tid < Hn) {
        float s = 0.f;
#pragma unroll
        for (int w = 0; w < 16; w++) s += sp[tid][w];
        s0l[tid] = s;
    }
    __syncthreads();
    float xv = x[b * Fn + f] + bo[0];
#pragma unroll
    for (int hh = 0; hh < Hn; hh++) {
        float zd = 0.f, zn = 0.f;
        const float* eqb = EqT + (size_t)hh * En * Fn + f;
#pragma unroll 8
        for (int e = 0; e < En; e++) {
            float eq = eqb[(size_t)e * Fn];
            zd = fmaf(eq, tt[hh * 64 + e], zd);
            zn = fmaf(eq, tt[256 + hh * 64 + e], zn);
        }
        xv += (s0l[hh] + hf * zn) / (1024.0f + hf * zd);
    }
    float s = wsum(xv);
    if (lane == 0) red[wid] = s;
    __syncthreads();
    float mu = 0.f;
#pragma unroll
    for (int w = 0; w < 16; w++) mu += red[w];
    mu *= (1.f / Fn);
    float dx = xv - mu;
    float vs = wsum(dx * dx);
    __syncthreads();
    if (lane == 0) red[wid] = vs;
    __syncthreads();
    float var = 0.f;
#pragma unroll
    for (int w = 0; w < 16; w++) var += red[w];
    var *= (1.f / Fn);
    float rs = rsqrtf(var + LN_EPS);
    out[b * Fn + f] = xv + bf2[f];
    h2T[f * Bn + b] = dx * rs * g2[f] + b2[f];
}

// ---- k4: ffn1 split-K-2 -> C1h (256 blocks x 512 thr), R16-P4 verified ----
__global__ __launch_bounds__(512) void k4(
    const float* __restrict__ h2T, const float* __restrict__ W1,
    float* __restrict__ C1h)
{
    __shared__ float sred[10240];   // [8 wid][64 lane][20 pad] = 40 KB
    const int bid = blockIdx.x, tid = threadIdx.x;
    const int wid = tid >> 6, lane = tid & 63;
    const int jg = bid & 127, half = bid >> 7;
    const int jq = lane & 7, bg = (lane >> 3) * 4;
    const float* wb = W1 + (size_t)(half * 512 + wid * 64) * FFn + jg * 32 + jq * 4;
    const float* hb = h2T + (size_t)(half * 512 + wid * 64) * Bn + bg;
    float4 a0 = {0,0,0,0}, a1 = {0,0,0,0}, a2 = {0,0,0,0}, a3 = {0,0,0,0};
#pragma unroll 8
    for (int f = 0; f < 64; f++) {
        float4 w4 = *(const float4*)&wb[(size_t)f * FFn];
        float4 h4 = *(const float4*)&hb[(size_t)f * Bn];
        FMA4(a0, h4.x, w4);
        FMA4(a1, h4.y, w4);
        FMA4(a2, h4.z, w4);
        FMA4(a3, h4.w, w4);
    }
    float* sp_ = &sred[(wid * 64 + lane) * 20];
    *(float4*)&sp_[0]  = a0;
    *(float4*)&sp_[4]  = a1;
    *(float4*)&sp_[8]  = a2;
    *(float4*)&sp_[12] = a3;
    __syncthreads();
#pragma unroll
    for (int r = 0; r < 2; r++) {
        int v = r * 512 + tid;
        int vl = v >> 4, k = v & 15;
        float acc = 0.f;
#pragma unroll
        for (int w = 0; w < 8; w++) acc += sred[(w * 64 + vl) * 20 + k];
        int jq2 = vl & 7, bgr = vl >> 3;
        int j = jg * 32 + jq2 * 4 + (k & 3);
        int bb = bgr * 4 + (k >> 2);
        C1h[((size_t)half * FFn + j) * Bn + bb] = acc;
    }
}

// ---- k5: ffn2 + folded {fc-2 reduce, bf1, gelu} stage (256 blocks x 512 thr),
// R16-P5 verified. atomicAdd into out (base written by k3).
__global__ __launch_bounds__(512) void k5(
    const float* __restrict__ C1h, const float* __restrict__ bf1,
    const float* __restrict__ W2, float* __restrict__ out)
{
    __shared__ float ug[256 * 32];   // 32 KB: [jj][b]
    const int bid = blockIdx.x, tid = threadIdx.x;
    const int wid = tid >> 6, lane = tid & 63;
    const int it = bid & 15, jc = bid >> 4;
    const float kk = 0.70710678118654752f;
    {
        const float4* b0p = (const float4*)(C1h + (size_t)jc * 256 * Bn);
        const float4* b1p = (const float4*)(C1h + ((size_t)FFn + jc * 256) * Bn);
#pragma unroll
        for (int k = 0; k < 4; k++) {
            int idx = k * 512 + tid;
            float4 s = b0p[idx];
            float4 c = b1p[idx];
            s.x += c.x; s.y += c.y; s.z += c.z; s.w += c.w;
            float bb = bf1[jc * 256 + (idx >> 3)];
            s.x += bb; s.y += bb; s.z += bb; s.w += bb;
            float4 g;
            g.x = 0.5f * s.x * (1.f + erff(s.x * kk));
            g.y = 0.5f * s.y * (1.f + erff(s.y * kk));
            g.z = 0.5f * s.z * (1.f + erff(s.z * kk));
            g.w = 0.5f * s.w * (1.f + erff(s.w * kk));
            ((float4*)ug)[idx] = g;
        }
    }
    __syncthreads();
    const int jg = lane >> 4, il = lane & 15;
    const int i0 = it * 64 + il * 4;
    const int bg = wid * 4;
    const float* wb = W2 + (size_t)(jc * 256 + jg) * Fn + i0;
    float4 a0 = {0,0,0,0}, a1 = {0,0,0,0}, a2 = {0,0,0,0}, a3 = {0,0,0,0};
#pragma unroll 8
    for (int jj0 = 0; jj0 < 256; jj0 += 4) {
        float4 w4 = *(const float4*)&wb[(size_t)jj0 * Fn];
        float4 u4 = *(const float4*)&ug[(jj0 + jg) * 32 + bg];
        FMA4(a0, u4.x, w4);
        FMA4(a1, u4.y, w4);
        FMA4(a2, u4.z, w4);
        FMA4(a3, u4.w, w4);
    }
    a0 = xr4(a0, 16); a0 = xr4(a0, 32);
    a1 = xr4(a1, 16); a1 = xr4(a1, 32);
    a2 = xr4(a2, 16); a2 = xr4(a2, 32);
    a3 = xr4(a3, 16); a3 = xr4(a3, 32);
    if (jg == 0) {
        float* ob = out + (size_t)bg * Fn + i0;
        atomicAdd(&ob[0 * Fn + 0], a0.x); atomicAdd(&ob[0 * Fn + 1], a0.y);
        atomicAdd(&ob[0 * Fn + 2], a0.z); atomicAdd(&ob[0 * Fn + 3], a0.w);
        atomicAdd(&ob[1 * Fn + 0], a1.x); atomicAdd(&ob[1 * Fn + 1], a1.y);
        atomicAdd(&ob[1 * Fn + 2], a1.z); atomicAdd(&ob[1 * Fn + 3], a1.w);
        atomicAdd(&ob[2 * Fn + 0], a2.x); atomicAdd(&ob[2 * Fn + 1], a2.y);
        atomicAdd(&ob[2 * Fn + 2], a2.z); atomicAdd(&ob[2 * Fn + 3], a2.w);
        atomicAdd(&ob[3 * Fn + 0], a3.x); atomicAdd(&ob[3 * Fn + 1], a3.y);
        atomicAdd(&ob[3 * Fn + 2], a3.z); atomicAdd(&ob[3 * Fn + 3], a3.w);
    }
}

extern "C" void kernel_launch(void* const* d_in, const int* in_sizes, int n_in,
                              void* d_out, int out_size, void* d_ws, size_t ws_size,
                              hipStream_t stream) {
    (void)in_sizes; (void)n_in; (void)out_size; (void)ws_size;
    const float* x   = (const float*)d_in[0];
    const float* emb = (const float*)d_in[1];
    const float* Wq  = (const float*)d_in[2];
    const float* Wk  = (const float*)d_in[3];
    const float* Wv  = (const float*)d_in[4];
    const float* Wo  = (const float*)d_in[5];
    const float* bo  = (const float*)d_in[6];
    const float* g1  = (const float*)d_in[7];
    const float* b1  = (const float*)d_in[8];
    const float* g2  = (const float*)d_in[9];
    const float* b2  = (const float*)d_in[10];
    const float* W1  = (const float*)d_in[11];
    const float* bf1 = (const float*)d_in[12];
    const float* W2  = (const float*)d_in[13];
    const float* bf2 = (const float*)d_in[14];
    float* out = (float*)d_out;

    float* ws = (float*)d_ws;
    size_t o = 0;
    float* EqT  = ws + o; o += (size_t)Hn * En * Fn;        // 262144
    float* Ekg  = ws + o; o += (size_t)Hn * Fn * En;        // 262144
    float* Evo  = ws + o; o += (size_t)Hn * Fn;             // 4096
    float* hbuf = ws + o; o += (size_t)Bn * Fn;             // 32768
    float* TT8  = ws + o; o += (size_t)8 * Hn * 64 * 64;    // 131072
    float* h2T  = ws + o; o += (size_t)Fn * Bn;             // 32768
    float* C1h  = ws + o; o += (size_t)2 * FFn * Bn;        // 262144

    k1<<<dim3(Bn + 256), 512, 0, stream>>>(x, g1, b1, emb, Wq, Wk, Wv, Wo,
                                           hbuf, EqT, Ekg, Evo);
    k2<<<dim3(512), 256, 0, stream>>>(hbuf, Evo, Ekg, TT8);
    k3<<<dim3(Bn), 1024, 0, stream>>>(x, hbuf, TT8, EqT, Evo, bo, g2, b2, bf2,
                                      out, h2T);
    k4<<<dim3(256), 512, 0, stream>>>(h2T, W1, C1h);
    k5<<<dim3(256), 512, 0, stream>>>(C1h, bf1, W2, out);
}